// Round 5
// baseline (69.771 us; speedup 1.0000x reference)
//
#include <hip/hip_runtime.h>
#include <math.h>

#define BB 4
#define NN 8192
#define LL 512
#define NSUB 1024
#define QPT 4                       // query points per thread
#define NSLICE 32
#define SLICE 256                   // target points per chamfer block
#define NCHUNK (NN / (256 * QPT))   // 8
#define SL_BLOCKS 48                // small-losses blocks in the z=8 slab
#define RED_BLOCKS 64

// ws layout:
// float ws[0..15]: 0=chamfer sum, 1=kl, 2=sizing, 3=material,
//                  4..7 density sum/b, 8..11 density sumsq/b, [12]=ticket cnt
// unsigned umax[2*BB*NN] at ws+16: order-preserving-key max of
//   h = p.q - 0.5|q|^2 per (dir,b,n); init 0 == smallest key
#define ACC_N 16
#define CNT_IDX 12
#define MAXARR_LEN (2 * BB * NN)

typedef float f2 __attribute__((ext_vector_type(2)));

__device__ inline f2 dup2(float v) { f2 r; r.x = v; r.y = v; return r; }
__device__ inline f2 mk2(float a, float b) { f2 r; r.x = a; r.y = b; return r; }

__device__ inline float max3f(float a, float b, float c) {
    float r;
    asm("v_max3_f32 %0, %1, %2, %3" : "=v"(r) : "v"(a), "v"(b), "v"(c));
    return r;
}

__device__ inline unsigned fkey(float f) {
    unsigned b = __float_as_uint(f);
    return (b & 0x80000000u) ? ~b : (b | 0x80000000u);
}
__device__ inline float fkeyinv(unsigned u) {
    unsigned b = (u & 0x80000000u) ? (u & 0x7FFFFFFFu) : ~u;
    return __uint_as_float(b);
}

__device__ inline float blockReduceSum256(float v) {
    __shared__ float red[4];
    #pragma unroll
    for (int o = 32; o; o >>= 1) v += __shfl_down(v, o);
    __syncthreads();
    if ((threadIdx.x & 63) == 0) red[threadIdx.x >> 6] = v;
    __syncthreads();
    return red[0] + red[1] + red[2] + red[3];
}

__global__ void init_ws_kernel(unsigned* __restrict__ ws) {
    const int total = ACC_N + MAXARR_LEN;
    for (int i = blockIdx.x * blockDim.x + threadIdx.x; i < total;
         i += gridDim.x * blockDim.x)
        ws[i] = 0u;
}

// grid (8, 32, 9):
//  z in 0..7 -> chamfer: chunk=x, slice=y, b=z>>1, dir=z&1
//  z == 8    -> v = y*8+x in 0..255: v<16 density; v<64 small-losses; else idle
__global__ __launch_bounds__(256) void mega_kernel(
    const float* __restrict__ pred, const float* __restrict__ targ,
    unsigned* __restrict__ umax,
    const float* __restrict__ mu, const float* __restrict__ logvar,
    const float* __restrict__ psiz, const float* __restrict__ tsiz,
    const float* __restrict__ pmat, const float* __restrict__ tmat,
    const int* __restrict__ sub_idx, float* __restrict__ ws) {
    __shared__ float4 sh[NSUB];     // chamfer uses first 4 KiB; density all 16
    const int tid = threadIdx.x;

    if (blockIdx.z < 8) {           // ---- chamfer ----
        const int chunk = blockIdx.x;
        const int slice = blockIdx.y;
        const int b = blockIdx.z >> 1;
        const int dir = blockIdx.z & 1;
        const float* __restrict__ P = dir ? targ : pred;
        const float* __restrict__ T = dir ? pred : targ;

        // Stage SLICE=256 points as packed pairs:
        //   shA[j2] = (x_{2j2}, x_{2j2+1}, y_{2j2}, y_{2j2+1})
        //   shB[j2] = (z_{2j2}, z_{2j2+1}, w_{2j2}, w_{2j2+1}), w = -0.5|q|^2
        {
            const float* tp = T + ((size_t)b * NN + slice * SLICE + tid) * 3;
            float x = tp[0], y = tp[1], z = tp[2];
            float w = -0.5f * fmaf(x, x, fmaf(y, y, z * z));
            float* fp = (float*)sh;
            const int j2 = tid >> 1, hf = tid & 1;
            fp[j2 * 4 + hf] = x;
            fp[j2 * 4 + 2 + hf] = y;
            fp[512 + j2 * 4 + hf] = z;
            fp[512 + j2 * 4 + 2 + hf] = w;
        }

        f2 px2[QPT], py2[QPT], pz2[QPT];
        float h[QPT];
        const int qbase = chunk * (256 * QPT) + tid;
        #pragma unroll
        for (int k = 0; k < QPT; ++k) {
            const float* p = P + ((size_t)b * NN + qbase + k * 256) * 3;
            px2[k] = dup2(p[0]); py2[k] = dup2(p[1]); pz2[k] = dup2(p[2]);
            h[k] = -1e30f;
        }
        __syncthreads();

        const float4* shA = sh;
        const float4* shB = sh + 128;
        #pragma unroll 4
        for (int j2 = 0; j2 < SLICE / 2; ++j2) {
            float4 A = shA[j2];
            float4 B = shB[j2];
            f2 qx = mk2(A.x, A.y), qy = mk2(A.z, A.w);
            f2 qz = mk2(B.x, B.y), qw = mk2(B.z, B.w);
            #pragma unroll
            for (int k = 0; k < QPT; ++k) {
                f2 t = __builtin_elementwise_fma(pz2[k], qz, qw);
                t = __builtin_elementwise_fma(py2[k], qy, t);
                t = __builtin_elementwise_fma(px2[k], qx, t);
                h[k] = max3f(h[k], t.x, t.y);
            }
        }

        unsigned* dst = umax + (size_t)dir * BB * NN + (size_t)b * NN + qbase;
        #pragma unroll
        for (int k = 0; k < QPT; ++k)
            atomicMax(dst + k * 256, fkey(h[k]));
        return;
    }

    const int v = blockIdx.y * 8 + blockIdx.x;   // 0..255
    if (v < 16) {                   // ---- density ----
        const int chunk = v & 3;
        const int b = v >> 2;
        for (int k = tid; k < NSUB; k += 256) {
            int idx = sub_idx[k];
            const float* p = pred + ((size_t)b * NN + idx) * 3;
            float x = p[0], y = p[1], z = p[2];
            sh[k] = make_float4(x, y, z, -0.5f * fmaf(x, x, fmaf(y, y, z * z)));
        }
        __syncthreads();
        const int i = chunk * 256 + tid;
        const float4 me = sh[i];
        float h0 = -1e30f, h1 = -1e30f, h2 = -1e30f, h3 = -1e30f;
        #pragma unroll 4
        for (int j = 0; j < NSUB; j += 4) {
            float4 q0 = sh[j + 0], q1 = sh[j + 1], q2 = sh[j + 2], q3 = sh[j + 3];
            float t0 = fmaf(me.z, q0.z, q0.w);
            t0 = fmaf(me.y, q0.y, t0); t0 = fmaf(me.x, q0.x, t0);
            t0 = (j + 0 == i) ? -1e30f : t0; h0 = fmaxf(h0, t0);
            float t1 = fmaf(me.z, q1.z, q1.w);
            t1 = fmaf(me.y, q1.y, t1); t1 = fmaf(me.x, q1.x, t1);
            t1 = (j + 1 == i) ? -1e30f : t1; h1 = fmaxf(h1, t1);
            float t2 = fmaf(me.z, q2.z, q2.w);
            t2 = fmaf(me.y, q2.y, t2); t2 = fmaf(me.x, q2.x, t2);
            t2 = (j + 2 == i) ? -1e30f : t2; h2 = fmaxf(h2, t2);
            float t3 = fmaf(me.z, q3.z, q3.w);
            t3 = fmaf(me.y, q3.y, t3); t3 = fmaf(me.x, q3.x, t3);
            t3 = (j + 3 == i) ? -1e30f : t3; h3 = fmaxf(h3, t3);
        }
        float h = fmaxf(fmaxf(h0, h1), fmaxf(h2, h3));
        float pp = fmaf(me.x, me.x, fmaf(me.y, me.y, me.z * me.z));
        float m = pp - 2.0f * h;        // nn squared distance
        float s = blockReduceSum256(m); __syncthreads();
        float ss = blockReduceSum256(m * m);
        if (tid == 0) {
            atomicAdd(&ws[4 + b], s);
            atomicAdd(&ws[8 + b], ss);
        }
    } else if (v < 16 + SL_BLOCKS) {  // ---- kl + sizing + material ----
        const int r = v - 16;
        const int stride = SL_BLOCKS * 256;
        const int g0 = r * 256 + tid;

        float skl = 0.0f;
        for (int i = g0; i < BB * LL; i += stride) {
            float m = mu[i], lv = logvar[i];
            skl += 1.0f + lv - m * m - expf(lv);
        }
        float ssz = 0.0f;
        for (int i = g0; i < BB * NN; i += stride) {
            float d = psiz[i] - tsiz[i];
            ssz = fmaf(d, d, ssz);
        }
        float smt = 0.0f;
        for (int i = g0; i < BB * NN * 4; i += stride) {
            float d = pmat[i] - tmat[i];
            smt = fmaf(d, d, smt);
        }
        skl = blockReduceSum256(skl); __syncthreads();
        ssz = blockReduceSum256(ssz); __syncthreads();
        smt = blockReduceSum256(smt);
        if (tid == 0) {
            atomicAdd(&ws[1], skl);
            atomicAdd(&ws[2], ssz);
            atomicAdd(&ws[3], smt);
        }
    }
}

// chamfer min-sum: d_min(n) = |p_n|^2 - 2*max_h(n); last block finalizes.
__global__ __launch_bounds__(256) void reduce_finalize_kernel(
    const float* __restrict__ pred, const float* __restrict__ targ,
    const unsigned* __restrict__ umax, float* __restrict__ ws,
    float* __restrict__ out) {
    const int stride = gridDim.x * blockDim.x;
    float s = 0.0f;
    for (int i = blockIdx.x * blockDim.x + threadIdx.x; i < MAXARR_LEN;
         i += stride) {
        float h = fkeyinv(umax[i]);
        int dir = i >> 15;
        int r = i & 32767;
        int b = r >> 13;
        int n = r & 8191;
        const float* p = (dir ? targ : pred) + ((size_t)b * NN + n) * 3;
        float pp = fmaf(p[0], p[0], fmaf(p[1], p[1], p[2] * p[2]));
        s += pp - 2.0f * h;
    }
    s = blockReduceSum256(s);
    if (threadIdx.x == 0) {
        atomicAdd(&ws[0], s);
        __threadfence();
        unsigned* cnt = (unsigned*)&ws[CNT_IDX];
        unsigned t = atomicAdd(cnt, 1u);
        if (t == RED_BLOCKS - 1) {
            float a[12];
            #pragma unroll
            for (int i = 0; i < 12; ++i) a[i] = atomicAdd(&ws[i], 0.0f);
            float cd = a[0] / (float)(BB * NN);
            float kl = -0.5f * a[1] / (float)(BB * LL);
            float sizing = a[2] / (float)(BB * NN);
            float material = a[3] / (float)(BB * NN * 4);
            float den = 0.0f;
            #pragma unroll
            for (int b = 0; b < BB; ++b) {
                float sm = a[4 + b], ss = a[8 + b];
                float var = (ss - sm * sm / (float)NSUB) / (float)(NSUB - 1);
                den += sqrtf(fmaxf(var, 0.0f));
            }
            den *= (1.0f / BB);
            out[0] = cd + 0.001f * kl + 0.1f * den + 0.05f * sizing +
                     0.1f * material;
        }
    }
}

extern "C" void kernel_launch(void* const* d_in, const int* in_sizes, int n_in,
                              void* d_out, int out_size, void* d_ws,
                              size_t ws_size, hipStream_t stream) {
    const float* pred_pos = (const float*)d_in[0];
    const float* pred_siz = (const float*)d_in[1];
    const float* pred_mat = (const float*)d_in[2];
    const float* targ_pos = (const float*)d_in[3];
    const float* targ_siz = (const float*)d_in[4];
    const float* targ_mat = (const float*)d_in[5];
    const float* mu = (const float*)d_in[6];
    const float* logvar = (const float*)d_in[7];
    const int* sub_idx = (const int*)d_in[8];
    float* out = (float*)d_out;
    float* ws = (float*)d_ws;
    unsigned* uws = (unsigned*)d_ws;
    unsigned* umax = uws + ACC_N;

    init_ws_kernel<<<64, 256, 0, stream>>>(uws);
    mega_kernel<<<dim3(NCHUNK, NSLICE, 9), 256, 0, stream>>>(
        pred_pos, targ_pos, umax, mu, logvar, pred_siz, targ_siz, pred_mat,
        targ_mat, sub_idx, ws);
    reduce_finalize_kernel<<<RED_BLOCKS, 256, 0, stream>>>(
        pred_pos, targ_pos, umax, ws, out);
}

// Round 6
// 63.986 us; speedup vs baseline: 1.0904x; 1.0904x over previous
//
#include <hip/hip_runtime.h>
#include <math.h>

#define BB 4
#define NN 8192
#define LL 512
#define NSUB 1024
#define QPT 16                      // query points per thread
#define NSLICE 64
#define SLICE 128                   // target points per chamfer block
#define NCHUNK (NN / (256 * QPT))   // 2
#define SL_BLOCKS 48                // small-losses blocks in the z=0 slab
#define RED_BLOCKS 64

// ws layout:
// float ws[0..15]: 0=chamfer sum, 1=kl, 2=sizing, 3=material,
//                  4..7 density sum/b, 8..11 density sumsq/b, [12]=ticket cnt
// unsigned umax[2*BB*NN] at ws+16: order-preserving-key max of
//   h = p.q - 0.5|q|^2 per (dir,b,n); init 0 == smallest key
#define ACC_N 16
#define CNT_IDX 12
#define MAXARR_LEN (2 * BB * NN)

typedef float f2 __attribute__((ext_vector_type(2)));

__device__ inline f2 dup2(float v) { f2 r; r.x = v; r.y = v; return r; }
__device__ inline f2 mk2(float a, float b) { f2 r; r.x = a; r.y = b; return r; }

__device__ inline float max3f(float a, float b, float c) {
    float r;
    asm("v_max3_f32 %0, %1, %2, %3" : "=v"(r) : "v"(a), "v"(b), "v"(c));
    return r;
}

__device__ inline unsigned fkey(float f) {
    unsigned b = __float_as_uint(f);
    return (b & 0x80000000u) ? ~b : (b | 0x80000000u);
}
__device__ inline float fkeyinv(unsigned u) {
    unsigned b = (u & 0x80000000u) ? (u & 0x7FFFFFFFu) : ~u;
    return __uint_as_float(b);
}

__device__ inline float blockReduceSum256(float v) {
    __shared__ float red[4];
    #pragma unroll
    for (int o = 32; o; o >>= 1) v += __shfl_down(v, o);
    __syncthreads();
    if ((threadIdx.x & 63) == 0) red[threadIdx.x >> 6] = v;
    __syncthreads();
    return red[0] + red[1] + red[2] + red[3];
}

__global__ void init_ws_kernel(unsigned* __restrict__ ws) {
    const int total = ACC_N + MAXARR_LEN;
    for (int i = blockIdx.x * blockDim.x + threadIdx.x; i < total;
         i += gridDim.x * blockDim.x)
        ws[i] = 0u;
}

// grid (2, 64, 9):
//  z == 0    -> aux: v = y*2+x in 0..127: v<16 density; v<64 small-losses;
//               else exit (dispatched FIRST so it overlaps chamfer)
//  z in 1..8 -> chamfer: chunk=x, slice=y, b=(z-1)>>1, dir=(z-1)&1
__global__ __launch_bounds__(256) void mega_kernel(
    const float* __restrict__ pred, const float* __restrict__ targ,
    unsigned* __restrict__ umax,
    const float* __restrict__ mu, const float* __restrict__ logvar,
    const float* __restrict__ psiz, const float* __restrict__ tsiz,
    const float* __restrict__ pmat, const float* __restrict__ tmat,
    const int* __restrict__ sub_idx, float* __restrict__ ws) {
    __shared__ float4 sh[NSUB];     // chamfer uses first 2 KiB; density all 16
    const int tid = threadIdx.x;

    if (blockIdx.z != 0) {          // ---- chamfer ----
        const int chunk = blockIdx.x;
        const int slice = blockIdx.y;
        const int zz = blockIdx.z - 1;
        const int b = zz >> 1;
        const int dir = zz & 1;
        const float* __restrict__ P = dir ? targ : pred;
        const float* __restrict__ T = dir ? pred : targ;

        // Stage SLICE=128 points as packed pairs (threads 0..127):
        //   fp[j2*4 + {0,1}] = x pair, fp[j2*4 + {2,3}] = y pair   (A half)
        //   fp[256 + j2*4 + {0,1}] = z pair, ... + {2,3} = w pair  (B half)
        if (tid < SLICE) {
            const float* tp = T + ((size_t)b * NN + slice * SLICE + tid) * 3;
            float x = tp[0], y = tp[1], z = tp[2];
            float w = -0.5f * fmaf(x, x, fmaf(y, y, z * z));
            float* fp = (float*)sh;
            const int j2 = tid >> 1, hf = tid & 1;
            fp[j2 * 4 + hf] = x;
            fp[j2 * 4 + 2 + hf] = y;
            fp[256 + j2 * 4 + hf] = z;
            fp[256 + j2 * 4 + 2 + hf] = w;
        }

        f2 px2[QPT], py2[QPT], pz2[QPT];
        float h[QPT];
        const int qbase = chunk * (256 * QPT) + tid;
        #pragma unroll
        for (int k = 0; k < QPT; ++k) {
            const float* p = P + ((size_t)b * NN + qbase + k * 256) * 3;
            px2[k] = dup2(p[0]); py2[k] = dup2(p[1]); pz2[k] = dup2(p[2]);
            h[k] = -1e30f;
        }
        __syncthreads();

        const float4* shA = sh;           // 64 packed A groups
        const float4* shB = sh + SLICE / 2;  // 64 packed B groups
        #pragma unroll 2
        for (int j2 = 0; j2 < SLICE / 2; ++j2) {
            float4 A = shA[j2];
            float4 B = shB[j2];
            f2 qx = mk2(A.x, A.y), qy = mk2(A.z, A.w);
            f2 qz = mk2(B.x, B.y), qw = mk2(B.z, B.w);
            #pragma unroll
            for (int k = 0; k < QPT; ++k) {
                f2 t = __builtin_elementwise_fma(pz2[k], qz, qw);
                t = __builtin_elementwise_fma(py2[k], qy, t);
                t = __builtin_elementwise_fma(px2[k], qx, t);
                h[k] = max3f(h[k], t.x, t.y);
            }
        }

        unsigned* dst = umax + (size_t)dir * BB * NN + (size_t)b * NN + qbase;
        #pragma unroll
        for (int k = 0; k < QPT; ++k)
            atomicMax(dst + k * 256, fkey(h[k]));
        return;
    }

    const int v = blockIdx.y * NCHUNK + blockIdx.x;   // 0..127
    if (v < 16) {                   // ---- density ----
        const int chunk = v & 3;
        const int b = v >> 2;
        for (int k = tid; k < NSUB; k += 256) {
            int idx = sub_idx[k];
            const float* p = pred + ((size_t)b * NN + idx) * 3;
            float x = p[0], y = p[1], z = p[2];
            sh[k] = make_float4(x, y, z, -0.5f * fmaf(x, x, fmaf(y, y, z * z)));
        }
        __syncthreads();
        const int i = chunk * 256 + tid;
        const float4 me = sh[i];
        float h0 = -1e30f, h1 = -1e30f, h2 = -1e30f, h3 = -1e30f;
        #pragma unroll 4
        for (int j = 0; j < NSUB; j += 4) {
            float4 q0 = sh[j + 0], q1 = sh[j + 1], q2 = sh[j + 2], q3 = sh[j + 3];
            float t0 = fmaf(me.z, q0.z, q0.w);
            t0 = fmaf(me.y, q0.y, t0); t0 = fmaf(me.x, q0.x, t0);
            t0 = (j + 0 == i) ? -1e30f : t0; h0 = fmaxf(h0, t0);
            float t1 = fmaf(me.z, q1.z, q1.w);
            t1 = fmaf(me.y, q1.y, t1); t1 = fmaf(me.x, q1.x, t1);
            t1 = (j + 1 == i) ? -1e30f : t1; h1 = fmaxf(h1, t1);
            float t2 = fmaf(me.z, q2.z, q2.w);
            t2 = fmaf(me.y, q2.y, t2); t2 = fmaf(me.x, q2.x, t2);
            t2 = (j + 2 == i) ? -1e30f : t2; h2 = fmaxf(h2, t2);
            float t3 = fmaf(me.z, q3.z, q3.w);
            t3 = fmaf(me.y, q3.y, t3); t3 = fmaf(me.x, q3.x, t3);
            t3 = (j + 3 == i) ? -1e30f : t3; h3 = fmaxf(h3, t3);
        }
        float h = fmaxf(fmaxf(h0, h1), fmaxf(h2, h3));
        float pp = fmaf(me.x, me.x, fmaf(me.y, me.y, me.z * me.z));
        float m = pp - 2.0f * h;        // nn squared distance
        float s = blockReduceSum256(m); __syncthreads();
        float ss = blockReduceSum256(m * m);
        if (tid == 0) {
            atomicAdd(&ws[4 + b], s);
            atomicAdd(&ws[8 + b], ss);
        }
    } else if (v < 16 + SL_BLOCKS) {  // ---- kl + sizing + material ----
        const int r = v - 16;
        const int stride = SL_BLOCKS * 256;
        const int g0 = r * 256 + tid;

        float skl = 0.0f;
        for (int i = g0; i < BB * LL; i += stride) {
            float m = mu[i], lv = logvar[i];
            skl += 1.0f + lv - m * m - expf(lv);
        }
        float ssz = 0.0f;
        for (int i = g0; i < BB * NN; i += stride) {
            float d = psiz[i] - tsiz[i];
            ssz = fmaf(d, d, ssz);
        }
        float smt = 0.0f;
        for (int i = g0; i < BB * NN * 4; i += stride) {
            float d = pmat[i] - tmat[i];
            smt = fmaf(d, d, smt);
        }
        skl = blockReduceSum256(skl); __syncthreads();
        ssz = blockReduceSum256(ssz); __syncthreads();
        smt = blockReduceSum256(smt);
        if (tid == 0) {
            atomicAdd(&ws[1], skl);
            atomicAdd(&ws[2], ssz);
            atomicAdd(&ws[3], smt);
        }
    }
}

// chamfer min-sum: d_min(n) = |p_n|^2 - 2*max_h(n); last block finalizes.
__global__ __launch_bounds__(256) void reduce_finalize_kernel(
    const float* __restrict__ pred, const float* __restrict__ targ,
    const unsigned* __restrict__ umax, float* __restrict__ ws,
    float* __restrict__ out) {
    const int stride = gridDim.x * blockDim.x;
    float s = 0.0f;
    for (int i = blockIdx.x * blockDim.x + threadIdx.x; i < MAXARR_LEN;
         i += stride) {
        float h = fkeyinv(umax[i]);
        int dir = i >> 15;
        int r = i & 32767;
        int b = r >> 13;
        int n = r & 8191;
        const float* p = (dir ? targ : pred) + ((size_t)b * NN + n) * 3;
        float pp = fmaf(p[0], p[0], fmaf(p[1], p[1], p[2] * p[2]));
        s += pp - 2.0f * h;
    }
    s = blockReduceSum256(s);
    if (threadIdx.x == 0) {
        atomicAdd(&ws[0], s);
        __threadfence();
        unsigned* cnt = (unsigned*)&ws[CNT_IDX];
        unsigned t = atomicAdd(cnt, 1u);
        if (t == RED_BLOCKS - 1) {
            float a[12];
            #pragma unroll
            for (int i = 0; i < 12; ++i) a[i] = atomicAdd(&ws[i], 0.0f);
            float cd = a[0] / (float)(BB * NN);
            float kl = -0.5f * a[1] / (float)(BB * LL);
            float sizing = a[2] / (float)(BB * NN);
            float material = a[3] / (float)(BB * NN * 4);
            float den = 0.0f;
            #pragma unroll
            for (int b = 0; b < BB; ++b) {
                float sm = a[4 + b], ss = a[8 + b];
                float var = (ss - sm * sm / (float)NSUB) / (float)(NSUB - 1);
                den += sqrtf(fmaxf(var, 0.0f));
            }
            den *= (1.0f / BB);
            out[0] = cd + 0.001f * kl + 0.1f * den + 0.05f * sizing +
                     0.1f * material;
        }
    }
}

extern "C" void kernel_launch(void* const* d_in, const int* in_sizes, int n_in,
                              void* d_out, int out_size, void* d_ws,
                              size_t ws_size, hipStream_t stream) {
    const float* pred_pos = (const float*)d_in[0];
    const float* pred_siz = (const float*)d_in[1];
    const float* pred_mat = (const float*)d_in[2];
    const float* targ_pos = (const float*)d_in[3];
    const float* targ_siz = (const float*)d_in[4];
    const float* targ_mat = (const float*)d_in[5];
    const float* mu = (const float*)d_in[6];
    const float* logvar = (const float*)d_in[7];
    const int* sub_idx = (const int*)d_in[8];
    float* out = (float*)d_out;
    float* ws = (float*)d_ws;
    unsigned* uws = (unsigned*)d_ws;
    unsigned* umax = uws + ACC_N;

    init_ws_kernel<<<64, 256, 0, stream>>>(uws);
    mega_kernel<<<dim3(NCHUNK, NSLICE, 9), 256, 0, stream>>>(
        pred_pos, targ_pos, umax, mu, logvar, pred_siz, targ_siz, pred_mat,
        targ_mat, sub_idx, ws);
    reduce_finalize_kernel<<<RED_BLOCKS, 256, 0, stream>>>(
        pred_pos, targ_pos, umax, ws, out);
}

// Round 7
// 53.019 us; speedup vs baseline: 1.3160x; 1.2069x over previous
//
#include <hip/hip_runtime.h>
#include <math.h>

#define BB 4
#define NN 8192
#define LL 512
#define NSUB 1024
#define SL_BLOCKS 48
#define RED_BLOCKS 64

// ws layout:
// float ws[0..15]: 0=chamfer sum, 1=kl, 2=sizing, 3=material,
//                  4..7 density sum/b, 8..11 density sumsq/b, [12]=ticket cnt
// unsigned umax[2*BB*NN] at ws+16 (byte 64): fkey-max of h per (dir,b,n)
// byte FRAG_OFF: bf16 fragment arrays (MFMA path): Apred|Atarg|Bpred|Btarg
#define ACC_N 16
#define CNT_IDX 12
#define MAXARR_LEN (2 * BB * NN)

// ---- MFMA-path geometry ----
#define QROWS 256                    // query rows per block (4 waves x 64)
#define QTILES (NN / QROWS)          // 32
#define TSLICE 1024                  // target points per block slice
#define NSLICE_M (NN / TSLICE)       // 8
#define FRAG_SET ((size_t)BB * NN * 32)                 // 1 MiB per set/role
#define FRAG_OFF ((size_t)(ACC_N * 4 + MAXARR_LEN * 4)) // 262208 (16-aligned)
#define WS_NEED (FRAG_OFF + 4 * FRAG_SET)

// ---- VALU-fallback geometry (R6) ----
#define VQPT 16
#define VNSLICE 64
#define VSLICE 128
#define VNCHUNK 2

typedef __bf16 bf16x8 __attribute__((ext_vector_type(8)));
typedef float f32x16 __attribute__((ext_vector_type(16)));
typedef float f2 __attribute__((ext_vector_type(2)));

__device__ inline f2 dup2(float v) { f2 r; r.x = v; r.y = v; return r; }
__device__ inline f2 mk2(float a, float b) { f2 r; r.x = a; r.y = b; return r; }

__device__ inline float max3f(float a, float b, float c) {
    float r;
    asm("v_max3_f32 %0, %1, %2, %3" : "=v"(r) : "v"(a), "v"(b), "v"(c));
    return r;
}

// order-preserving float <-> uint32 key
__device__ inline unsigned fkey(float f) {
    unsigned b = __float_as_uint(f);
    return (b & 0x80000000u) ? ~b : (b | 0x80000000u);
}
__device__ inline float fkeyinv(unsigned u) {
    unsigned b = (u & 0x80000000u) ? (u & 0x7FFFFFFFu) : ~u;
    return __uint_as_float(b);
}

// f32 -> bf16 (RNE) and back, as raw ushort
__device__ inline unsigned short f2bf(float f) {
    unsigned u = __float_as_uint(f);
    unsigned r = (u + 0x7FFFu + ((u >> 16) & 1u)) >> 16;
    return (unsigned short)r;
}
__device__ inline float bf2f(unsigned short h) {
    return __uint_as_float(((unsigned)h) << 16);
}

__device__ inline unsigned pk(unsigned short lo, unsigned short hi) {
    return (unsigned)lo | ((unsigned)hi << 16);
}

__device__ inline float blockReduceSum256(float v) {
    __shared__ float red[4];
    #pragma unroll
    for (int o = 32; o; o >>= 1) v += __shfl_down(v, o);
    __syncthreads();
    if ((threadIdx.x & 63) == 0) red[threadIdx.x >> 6] = v;
    __syncthreads();
    return red[0] + red[1] + red[2] + red[3];
}

__global__ void init_ws_kernel(unsigned* __restrict__ ws) {
    const int total = ACC_N + MAXARR_LEN;
    for (int i = blockIdx.x * blockDim.x + threadIdx.x; i < total;
         i += gridDim.x * blockDim.x)
        ws[i] = 0u;
}

// Build MFMA fragments. K map (A entry / B entry):
//  0-2: ph,qh  3-5: pl,qh  6-8: ph,ql  9-11: pl,ql  -> (ph+pl)·(qh+ql)
//  12: 1,wh  13: 1,wl  14: 1,wl2  15: 0,0           -> w = -0.5|q|^2
// A stored point-major: [pt][k0..15] (32B). B stored tile-swizzled:
// byte = b*NN*32 + (p>>5)*1024 + khalf*512 + (p&31)*16.
__global__ __launch_bounds__(256) void prep_frags_kernel(
    const float* __restrict__ pred, const float* __restrict__ targ,
    unsigned char* __restrict__ frag) {
    const int i = blockIdx.x * 256 + threadIdx.x;   // 0 .. 2*BB*NN-1
    const int s = i >> 15;
    const int r = i & (BB * NN - 1);
    const int b = r >> 13;
    const int p = r & (NN - 1);
    const float* pos = (s ? targ : pred) + (size_t)r * 3;
    const float x = pos[0], y = pos[1], z = pos[2];
    const unsigned short hx = f2bf(x), hy = f2bf(y), hz = f2bf(z);
    const unsigned short lx = f2bf(x - bf2f(hx));
    const unsigned short ly = f2bf(y - bf2f(hy));
    const unsigned short lz = f2bf(z - bf2f(hz));
    const float w = -0.5f * fmaf(x, x, fmaf(y, y, z * z));
    const unsigned short wh = f2bf(w);
    const float wr = w - bf2f(wh);
    const unsigned short wl = f2bf(wr);
    const unsigned short wl2 = f2bf(wr - bf2f(wl));
    const unsigned short ONE = 0x3F80;

    uint4 a0, a1, b0, b1;
    a0.x = pk(hx, hy); a0.y = pk(hz, lx); a0.z = pk(ly, lz); a0.w = pk(hx, hy);
    a1.x = pk(hz, lx); a1.y = pk(ly, lz); a1.z = pk(ONE, ONE); a1.w = pk(ONE, 0);
    b0.x = pk(hx, hy); b0.y = pk(hz, hx); b0.z = pk(hy, hz); b0.w = pk(lx, ly);
    b1.x = pk(lz, lx); b1.y = pk(ly, lz); b1.z = pk(wh, wl); b1.w = pk(wl2, 0);

    uint4* Adst = (uint4*)(frag + (size_t)s * FRAG_SET) + (size_t)r * 2;
    Adst[0] = a0;
    Adst[1] = a1;
    uint4* Bdst = (uint4*)(frag + (2 + s) * FRAG_SET);
    const size_t bi = (size_t)b * NN * 2 + (size_t)(p >> 5) * 64 + (p & 31);
    Bdst[bi] = b0;
    Bdst[bi + 32] = b1;
}

// grid (32, 8, 9):
//  z in 1..8 -> MFMA chamfer: qtile=x, slice=y, b=(z-1)>>1, dir=(z-1)&1
//  z == 0    -> aux: v = y*32+x: v<16 density; v<64 small-losses; else exit
__global__ __launch_bounds__(256, 4) void mega_mfma_kernel(
    const float* __restrict__ pred, const float* __restrict__ targ,
    const unsigned char* __restrict__ frag, unsigned* __restrict__ umax,
    const float* __restrict__ mu, const float* __restrict__ logvar,
    const float* __restrict__ psiz, const float* __restrict__ tsiz,
    const float* __restrict__ pmat, const float* __restrict__ tmat,
    const int* __restrict__ sub_idx, float* __restrict__ ws) {
    __shared__ __align__(16) unsigned char smem[32768];
    const int tid = threadIdx.x;

    if (blockIdx.z != 0) {          // ---- chamfer via MFMA ----
        const int zz = blockIdx.z - 1;
        const int b = zz >> 1;
        const int dir = zz & 1;
        const int As = dir;          // query set
        const int Bs = dir ^ 1;      // target set
        const int w = tid >> 6, lane = tid & 63;
        const int lo5 = lane & 31, sel = lane >> 5;

        // stage B slice (32 KiB, straight coalesced copy; already swizzled)
        const uint4* src = (const uint4*)(frag + (size_t)(2 + Bs) * FRAG_SET) +
                           ((size_t)b * NN + (size_t)blockIdx.y * TSLICE) * 2;
        uint4* l4 = (uint4*)smem;
        #pragma unroll
        for (int i = 0; i < 8; ++i) l4[tid + 256 * i] = src[tid + 256 * i];

        // A fragments: 2 query tiles of 32 rows per wave
        const int qbase = blockIdx.x * QROWS + w * 64;
        const uint4* Ap = (const uint4*)(frag + (size_t)As * FRAG_SET) +
                          (size_t)b * NN * 2;
        const uint4 a0u = Ap[(size_t)(qbase + lo5) * 2 + sel];
        const uint4 a1u = Ap[(size_t)(qbase + 32 + lo5) * 2 + sel];
        const bf16x8 A0 = __builtin_bit_cast(bf16x8, a0u);
        const bf16x8 A1 = __builtin_bit_cast(bf16x8, a1u);
        __syncthreads();

        f32x16 st0, st1;
        #pragma unroll
        for (int i = 0; i < 16; ++i) { st0[i] = -1e30f; st1[i] = -1e30f; }
        const f32x16 zc = {};
        const bf16x8* lsb = (const bf16x8*)smem;
        const int boff = sel * 32 + lo5;

        #pragma unroll 2
        for (int mt = 0; mt < TSLICE / 32; ++mt) {
            const bf16x8 Bv = lsb[mt * 64 + boff];
            f32x16 d0 = __builtin_amdgcn_mfma_f32_32x32x16_bf16(A0, Bv, zc, 0, 0, 0);
            f32x16 d1 = __builtin_amdgcn_mfma_f32_32x32x16_bf16(A1, Bv, zc, 0, 0, 0);
            #pragma unroll
            for (int i = 0; i < 16; ++i) {
                st0[i] = fmaxf(st0[i], d0[i]);
                st1[i] = fmaxf(st1[i], d1[i]);
            }
        }

        // max over target columns: butterfly across the 32 col-lanes
        #pragma unroll
        for (int m = 1; m <= 16; m <<= 1) {
            #pragma unroll
            for (int i = 0; i < 16; ++i) {
                st0[i] = fmaxf(st0[i], __shfl_xor(st0[i], m));
                st1[i] = fmaxf(st1[i], __shfl_xor(st1[i], m));
            }
        }
        if (lo5 == 0) {
            unsigned* dst = umax + (size_t)dir * BB * NN + (size_t)b * NN + qbase;
            #pragma unroll
            for (int i = 0; i < 16; ++i) {
                const int rr = (i & 3) + 8 * (i >> 2) + 4 * sel;
                atomicMax(dst + rr, fkey(st0[i]));
                atomicMax(dst + 32 + rr, fkey(st1[i]));
            }
        }
        return;
    }

    const int v = blockIdx.y * 32 + blockIdx.x;   // 0..255
    if (v < 16) {                   // ---- density ----
        float4* pts = (float4*)smem;
        const int chunk = v & 3;
        const int b = v >> 2;
        for (int k = tid; k < NSUB; k += 256) {
            int idx = sub_idx[k];
            const float* p = pred + ((size_t)b * NN + idx) * 3;
            float x = p[0], y = p[1], z = p[2];
            pts[k] = make_float4(x, y, z, -0.5f * fmaf(x, x, fmaf(y, y, z * z)));
        }
        __syncthreads();
        const int i = chunk * 256 + tid;
        const float4 me = pts[i];
        float h0 = -1e30f, h1 = -1e30f, h2 = -1e30f, h3 = -1e30f;
        #pragma unroll 4
        for (int j = 0; j < NSUB; j += 4) {
            float4 q0 = pts[j + 0], q1 = pts[j + 1], q2 = pts[j + 2], q3 = pts[j + 3];
            float t0 = fmaf(me.z, q0.z, q0.w);
            t0 = fmaf(me.y, q0.y, t0); t0 = fmaf(me.x, q0.x, t0);
            t0 = (j + 0 == i) ? -1e30f : t0; h0 = fmaxf(h0, t0);
            float t1 = fmaf(me.z, q1.z, q1.w);
            t1 = fmaf(me.y, q1.y, t1); t1 = fmaf(me.x, q1.x, t1);
            t1 = (j + 1 == i) ? -1e30f : t1; h1 = fmaxf(h1, t1);
            float t2 = fmaf(me.z, q2.z, q2.w);
            t2 = fmaf(me.y, q2.y, t2); t2 = fmaf(me.x, q2.x, t2);
            t2 = (j + 2 == i) ? -1e30f : t2; h2 = fmaxf(h2, t2);
            float t3 = fmaf(me.z, q3.z, q3.w);
            t3 = fmaf(me.y, q3.y, t3); t3 = fmaf(me.x, q3.x, t3);
            t3 = (j + 3 == i) ? -1e30f : t3; h3 = fmaxf(h3, t3);
        }
        float h = fmaxf(fmaxf(h0, h1), fmaxf(h2, h3));
        float pp = fmaf(me.x, me.x, fmaf(me.y, me.y, me.z * me.z));
        float m = pp - 2.0f * h;
        float s = blockReduceSum256(m); __syncthreads();
        float ss = blockReduceSum256(m * m);
        if (tid == 0) {
            atomicAdd(&ws[4 + b], s);
            atomicAdd(&ws[8 + b], ss);
        }
    } else if (v < 16 + SL_BLOCKS) {  // ---- kl + sizing + material ----
        const int r = v - 16;
        const int stride = SL_BLOCKS * 256;
        const int g0 = r * 256 + tid;
        float skl = 0.0f;
        for (int i = g0; i < BB * LL; i += stride) {
            float m = mu[i], lv = logvar[i];
            skl += 1.0f + lv - m * m - expf(lv);
        }
        float ssz = 0.0f;
        for (int i = g0; i < BB * NN; i += stride) {
            float d = psiz[i] - tsiz[i];
            ssz = fmaf(d, d, ssz);
        }
        float smt = 0.0f;
        for (int i = g0; i < BB * NN * 4; i += stride) {
            float d = pmat[i] - tmat[i];
            smt = fmaf(d, d, smt);
        }
        skl = blockReduceSum256(skl); __syncthreads();
        ssz = blockReduceSum256(ssz); __syncthreads();
        smt = blockReduceSum256(smt);
        if (tid == 0) {
            atomicAdd(&ws[1], skl);
            atomicAdd(&ws[2], ssz);
            atomicAdd(&ws[3], smt);
        }
    }
}

// ---- VALU fallback (R6), used only if ws_size < WS_NEED ----
__global__ __launch_bounds__(256) void mega_valu_kernel(
    const float* __restrict__ pred, const float* __restrict__ targ,
    unsigned* __restrict__ umax,
    const float* __restrict__ mu, const float* __restrict__ logvar,
    const float* __restrict__ psiz, const float* __restrict__ tsiz,
    const float* __restrict__ pmat, const float* __restrict__ tmat,
    const int* __restrict__ sub_idx, float* __restrict__ ws) {
    __shared__ float4 sh[NSUB];
    const int tid = threadIdx.x;
    if (blockIdx.z != 0) {
        const int chunk = blockIdx.x;
        const int slice = blockIdx.y;
        const int zz = blockIdx.z - 1;
        const int b = zz >> 1;
        const int dir = zz & 1;
        const float* __restrict__ P = dir ? targ : pred;
        const float* __restrict__ T = dir ? pred : targ;
        if (tid < VSLICE) {
            const float* tp = T + ((size_t)b * NN + slice * VSLICE + tid) * 3;
            float x = tp[0], y = tp[1], z = tp[2];
            float w = -0.5f * fmaf(x, x, fmaf(y, y, z * z));
            float* fp = (float*)sh;
            const int j2 = tid >> 1, hf = tid & 1;
            fp[j2 * 4 + hf] = x;
            fp[j2 * 4 + 2 + hf] = y;
            fp[256 + j2 * 4 + hf] = z;
            fp[256 + j2 * 4 + 2 + hf] = w;
        }
        f2 px2[VQPT], py2[VQPT], pz2[VQPT];
        float h[VQPT];
        const int qbase = chunk * (256 * VQPT) + tid;
        #pragma unroll
        for (int k = 0; k < VQPT; ++k) {
            const float* p = P + ((size_t)b * NN + qbase + k * 256) * 3;
            px2[k] = dup2(p[0]); py2[k] = dup2(p[1]); pz2[k] = dup2(p[2]);
            h[k] = -1e30f;
        }
        __syncthreads();
        const float4* shA = sh;
        const float4* shB = sh + VSLICE / 2;
        #pragma unroll 2
        for (int j2 = 0; j2 < VSLICE / 2; ++j2) {
            float4 A = shA[j2];
            float4 B = shB[j2];
            f2 qx = mk2(A.x, A.y), qy = mk2(A.z, A.w);
            f2 qz = mk2(B.x, B.y), qw = mk2(B.z, B.w);
            #pragma unroll
            for (int k = 0; k < VQPT; ++k) {
                f2 t = __builtin_elementwise_fma(pz2[k], qz, qw);
                t = __builtin_elementwise_fma(py2[k], qy, t);
                t = __builtin_elementwise_fma(px2[k], qx, t);
                h[k] = max3f(h[k], t.x, t.y);
            }
        }
        unsigned* dst = umax + (size_t)dir * BB * NN + (size_t)b * NN + qbase;
        #pragma unroll
        for (int k = 0; k < VQPT; ++k)
            atomicMax(dst + k * 256, fkey(h[k]));
        return;
    }
    const int v = blockIdx.y * VNCHUNK + blockIdx.x;
    if (v < 16) {
        const int chunk = v & 3;
        const int b = v >> 2;
        for (int k = tid; k < NSUB; k += 256) {
            int idx = sub_idx[k];
            const float* p = pred + ((size_t)b * NN + idx) * 3;
            float x = p[0], y = p[1], z = p[2];
            sh[k] = make_float4(x, y, z, -0.5f * fmaf(x, x, fmaf(y, y, z * z)));
        }
        __syncthreads();
        const int i = chunk * 256 + tid;
        const float4 me = sh[i];
        float h0 = -1e30f, h1 = -1e30f, h2 = -1e30f, h3 = -1e30f;
        #pragma unroll 4
        for (int j = 0; j < NSUB; j += 4) {
            float4 q0 = sh[j + 0], q1 = sh[j + 1], q2 = sh[j + 2], q3 = sh[j + 3];
            float t0 = fmaf(me.z, q0.z, q0.w);
            t0 = fmaf(me.y, q0.y, t0); t0 = fmaf(me.x, q0.x, t0);
            t0 = (j + 0 == i) ? -1e30f : t0; h0 = fmaxf(h0, t0);
            float t1 = fmaf(me.z, q1.z, q1.w);
            t1 = fmaf(me.y, q1.y, t1); t1 = fmaf(me.x, q1.x, t1);
            t1 = (j + 1 == i) ? -1e30f : t1; h1 = fmaxf(h1, t1);
            float t2 = fmaf(me.z, q2.z, q2.w);
            t2 = fmaf(me.y, q2.y, t2); t2 = fmaf(me.x, q2.x, t2);
            t2 = (j + 2 == i) ? -1e30f : t2; h2 = fmaxf(h2, t2);
            float t3 = fmaf(me.z, q3.z, q3.w);
            t3 = fmaf(me.y, q3.y, t3); t3 = fmaf(me.x, q3.x, t3);
            t3 = (j + 3 == i) ? -1e30f : t3; h3 = fmaxf(h3, t3);
        }
        float h = fmaxf(fmaxf(h0, h1), fmaxf(h2, h3));
        float pp = fmaf(me.x, me.x, fmaf(me.y, me.y, me.z * me.z));
        float m = pp - 2.0f * h;
        float s = blockReduceSum256(m); __syncthreads();
        float ss = blockReduceSum256(m * m);
        if (tid == 0) {
            atomicAdd(&ws[4 + b], s);
            atomicAdd(&ws[8 + b], ss);
        }
    } else if (v < 16 + SL_BLOCKS) {
        const int r = v - 16;
        const int stride = SL_BLOCKS * 256;
        const int g0 = r * 256 + tid;
        float skl = 0.0f;
        for (int i = g0; i < BB * LL; i += stride) {
            float m = mu[i], lv = logvar[i];
            skl += 1.0f + lv - m * m - expf(lv);
        }
        float ssz = 0.0f;
        for (int i = g0; i < BB * NN; i += stride) {
            float d = psiz[i] - tsiz[i];
            ssz = fmaf(d, d, ssz);
        }
        float smt = 0.0f;
        for (int i = g0; i < BB * NN * 4; i += stride) {
            float d = pmat[i] - tmat[i];
            smt = fmaf(d, d, smt);
        }
        skl = blockReduceSum256(skl); __syncthreads();
        ssz = blockReduceSum256(ssz); __syncthreads();
        smt = blockReduceSum256(smt);
        if (tid == 0) {
            atomicAdd(&ws[1], skl);
            atomicAdd(&ws[2], ssz);
            atomicAdd(&ws[3], smt);
        }
    }
}

// chamfer min-sum: d_min(n) = |p_n|^2 - 2*max_h(n); last block finalizes.
__global__ __launch_bounds__(256) void reduce_finalize_kernel(
    const float* __restrict__ pred, const float* __restrict__ targ,
    const unsigned* __restrict__ umax, float* __restrict__ ws,
    float* __restrict__ out) {
    const int stride = gridDim.x * blockDim.x;
    float s = 0.0f;
    for (int i = blockIdx.x * blockDim.x + threadIdx.x; i < MAXARR_LEN;
         i += stride) {
        float h = fkeyinv(umax[i]);
        int dir = i >> 15;
        int r = i & 32767;
        int b = r >> 13;
        int n = r & 8191;
        const float* p = (dir ? targ : pred) + ((size_t)b * NN + n) * 3;
        float pp = fmaf(p[0], p[0], fmaf(p[1], p[1], p[2] * p[2]));
        s += pp - 2.0f * h;
    }
    s = blockReduceSum256(s);
    if (threadIdx.x == 0) {
        atomicAdd(&ws[0], s);
        __threadfence();
        unsigned* cnt = (unsigned*)&ws[CNT_IDX];
        unsigned t = atomicAdd(cnt, 1u);
        if (t == RED_BLOCKS - 1) {
            float a[12];
            #pragma unroll
            for (int i = 0; i < 12; ++i) a[i] = atomicAdd(&ws[i], 0.0f);
            float cd = a[0] / (float)(BB * NN);
            float kl = -0.5f * a[1] / (float)(BB * LL);
            float sizing = a[2] / (float)(BB * NN);
            float material = a[3] / (float)(BB * NN * 4);
            float den = 0.0f;
            #pragma unroll
            for (int b = 0; b < BB; ++b) {
                float sm = a[4 + b], ss = a[8 + b];
                float var = (ss - sm * sm / (float)NSUB) / (float)(NSUB - 1);
                den += sqrtf(fmaxf(var, 0.0f));
            }
            den *= (1.0f / BB);
            out[0] = cd + 0.001f * kl + 0.1f * den + 0.05f * sizing +
                     0.1f * material;
        }
    }
}

extern "C" void kernel_launch(void* const* d_in, const int* in_sizes, int n_in,
                              void* d_out, int out_size, void* d_ws,
                              size_t ws_size, hipStream_t stream) {
    const float* pred_pos = (const float*)d_in[0];
    const float* pred_siz = (const float*)d_in[1];
    const float* pred_mat = (const float*)d_in[2];
    const float* targ_pos = (const float*)d_in[3];
    const float* targ_siz = (const float*)d_in[4];
    const float* targ_mat = (const float*)d_in[5];
    const float* mu = (const float*)d_in[6];
    const float* logvar = (const float*)d_in[7];
    const int* sub_idx = (const int*)d_in[8];
    float* out = (float*)d_out;
    float* ws = (float*)d_ws;
    unsigned* uws = (unsigned*)d_ws;
    unsigned* umax = uws + ACC_N;
    unsigned char* frag = (unsigned char*)d_ws + FRAG_OFF;

    init_ws_kernel<<<64, 256, 0, stream>>>(uws);
    if (ws_size >= WS_NEED) {
        prep_frags_kernel<<<(2 * BB * NN) / 256, 256, 0, stream>>>(
            pred_pos, targ_pos, frag);
        mega_mfma_kernel<<<dim3(QTILES, NSLICE_M, 9), 256, 0, stream>>>(
            pred_pos, targ_pos, frag, umax, mu, logvar, pred_siz, targ_siz,
            pred_mat, targ_mat, sub_idx, ws);
    } else {
        mega_valu_kernel<<<dim3(VNCHUNK, VNSLICE, 9), 256, 0, stream>>>(
            pred_pos, targ_pos, umax, mu, logvar, pred_siz, targ_siz,
            pred_mat, targ_mat, sub_idx, ws);
    }
    reduce_finalize_kernel<<<RED_BLOCKS, 256, 0, stream>>>(
        pred_pos, targ_pos, umax, ws, out);
}